// Round 1
// baseline (652.686 us; speedup 1.0000x reference)
//
#include <hip/hip_runtime.h>

typedef __bf16 bf16x8 __attribute__((ext_vector_type(8)));
typedef __bf16 bf16x4 __attribute__((ext_vector_type(4)));
typedef float f32x4 __attribute__((ext_vector_type(4)));

#define MFMA16(a,b,c) __builtin_amdgcn_mfma_f32_16x16x32_bf16((a),(b),(c),0,0,0)

#define BB   16
#define SEQ  1024
#define CD   768
#define NHD  12
#define HDD  64
#define HID  3072
#define MT   (BB*SEQ)   // 16384

__device__ __forceinline__ void gload16(const void* g, void* l) {
    __builtin_amdgcn_global_load_lds(
        (const __attribute__((address_space(1))) void*)g,
        (__attribute__((address_space(3))) void*)l, 16, 0, 0);
}

// ---------------- weight transpose: fp32 [R][C] -> bf16 [C][R] ----------------
__global__ __launch_bounds__(256)
void transpose_w(const float* __restrict__ W, __bf16* __restrict__ WT, int R, int C)
{
    __shared__ float t[32][33];
    int tc = C >> 5;
    int bid = blockIdx.x;
    int br = bid / tc, bc = bid % tc;
    int x = threadIdx.x & 31, y = threadIdx.x >> 5; // y: 0..7
#pragma unroll
    for (int i = 0; i < 4; ++i)
        t[y + 8*i][x] = W[(size_t)(br*32 + y + 8*i)*C + bc*32 + x];
    __syncthreads();
#pragma unroll
    for (int i = 0; i < 4; ++i)
        WT[(size_t)(bc*32 + y + 8*i)*R + br*32 + x] = (__bf16)t[x][y + 8*i];
}

// ---------------- batched bf16 transpose: v[bh][1024][64] -> vT[bh][64][1024] --
__global__ __launch_bounds__(256)
void transpose_v(const __bf16* __restrict__ V, __bf16* __restrict__ VT)
{
    __shared__ __bf16 t[32][34];
    int bid = blockIdx.x;
    int bh = bid >> 6;          // 64 tiles per batch: 32 (n) x 2 (d)
    int tt = bid & 63;
    int br = tt >> 1;           // n-tile 0..31
    int bc = tt & 1;            // d-tile 0..1
    const __bf16* src = V + (size_t)bh * SEQ * HDD;
    __bf16* dst = VT + (size_t)bh * HDD * SEQ;
    int x = threadIdx.x & 31, y = threadIdx.x >> 5;
#pragma unroll
    for (int i = 0; i < 4; ++i)
        t[y + 8*i][x] = src[(size_t)(br*32 + y + 8*i)*HDD + bc*32 + x];
    __syncthreads();
#pragma unroll
    for (int i = 0; i < 4; ++i)
        dst[(size_t)(bc*32 + y + 8*i)*SEQ + br*32 + x] = t[x][y + 8*i];
}

// ---------------- LayerNorm: fp32 [M][768] -> bf16 [M][768] -------------------
__global__ __launch_bounds__(256)
void ln_kernel(const float* __restrict__ xin, const float* __restrict__ g,
               const float* __restrict__ bb, __bf16* out)
{
    int row = blockIdx.x * 4 + (threadIdx.x >> 6);
    int lane = threadIdx.x & 63;
    const float* xr = xin + (size_t)row * CD + lane * 4;
    float4 v0 = *(const float4*)(xr);
    float4 v1 = *(const float4*)(xr + 256);
    float4 v2 = *(const float4*)(xr + 512);
    float s = v0.x+v0.y+v0.z+v0.w + v1.x+v1.y+v1.z+v1.w + v2.x+v2.y+v2.z+v2.w;
#pragma unroll
    for (int off = 1; off < 64; off <<= 1) s += __shfl_xor(s, off);
    float mu = s * (1.0f/768.0f);
    float q =
        (v0.x-mu)*(v0.x-mu)+(v0.y-mu)*(v0.y-mu)+(v0.z-mu)*(v0.z-mu)+(v0.w-mu)*(v0.w-mu)+
        (v1.x-mu)*(v1.x-mu)+(v1.y-mu)*(v1.y-mu)+(v1.z-mu)*(v1.z-mu)+(v1.w-mu)*(v1.w-mu)+
        (v2.x-mu)*(v2.x-mu)+(v2.y-mu)*(v2.y-mu)+(v2.z-mu)*(v2.z-mu)+(v2.w-mu)*(v2.w-mu);
#pragma unroll
    for (int off = 1; off < 64; off <<= 1) q += __shfl_xor(q, off);
    float rstd = rsqrtf(q * (1.0f/768.0f) + 1e-5f);

    __bf16* orow = out + (size_t)row * CD + lane * 4;
#pragma unroll
    for (int p = 0; p < 3; ++p) {
        float4 xv = (p == 0) ? v0 : (p == 1) ? v1 : v2;
        float4 gv = *(const float4*)(g  + p*256 + lane*4);
        float4 bv = *(const float4*)(bb + p*256 + lane*4);
        bf16x4 ov;
        ov[0] = (__bf16)((xv.x-mu)*rstd*gv.x + bv.x);
        ov[1] = (__bf16)((xv.y-mu)*rstd*gv.y + bv.y);
        ov[2] = (__bf16)((xv.z-mu)*rstd*gv.z + bv.z);
        ov[3] = (__bf16)((xv.w-mu)*rstd*gv.w + bv.w);
        *(bf16x4*)(orow + p*256) = ov;
    }
}

// ---------------- GEMM: A[M,K] bf16 @ BT[N,K] bf16 -> epilogue ----------------
// EPI 0: qkv scatter (bf16 -> q,k,v [B,H,N,64])
// EPI 1: outf[r,c] = res[r,c] + acc + bias (fp32)
// EPI 2: outb[r,c] = gelu(acc + bias) (bf16)
template<int EPI>
__global__ __launch_bounds__(256)
void gemm_bt(const __bf16* __restrict__ A, const __bf16* __restrict__ BT,
             const float* __restrict__ bias,
             const float* res, float* outf,
             __bf16* __restrict__ outb,
             __bf16* __restrict__ qb, __bf16* __restrict__ kb, __bf16* __restrict__ vb,
             int M, int N, int K)
{
    __shared__ alignas(16) __bf16 lsA[128*64];
    __shared__ alignas(16) __bf16 lsB[128*64];

    int nbn = N >> 7;
    int nwg = (M >> 7) * nbn;
    int bid = (int)blockIdx.x;
    int cpx = nwg >> 3;                       // all our grids are %8 == 0
    int sw = (bid & 7) * cpx + (bid >> 3);    // XCD-contiguous swizzle
    int bm = sw / nbn, bn = sw % nbn;
    int row0 = bm << 7, col0 = bn << 7;

    int tid = threadIdx.x;
    int lane = tid & 63, w = tid >> 6;
    int wr = w >> 1, wc = w & 1;
    int lr = lane & 15, lg = lane >> 4;

    char* lA = (char*)lsA;
    char* lB = (char*)lsB;

    f32x4 acc[4][4] = {};
    int sbase = w * 4096 + lane * 16;
    int swz = (lr & 7) << 4;

    for (int kt = 0; kt < K; kt += 64) {
        __syncthreads();
#pragma unroll
        for (int i = 0; i < 4; ++i) {
            int s = sbase + (i << 10);
            int r = s >> 7;
            int ch = ((s >> 4) & 7) ^ (r & 7);   // inverse-swizzled source chunk
            gload16(A  + (size_t)(row0 + r)*K + (kt + ch*8), lA + (w*4 + i)*1024);
            gload16(BT + (size_t)(col0 + r)*K + (kt + ch*8), lB + (w*4 + i)*1024);
        }
        __syncthreads();

#pragma unroll
        for (int ks = 0; ks < 2; ++ks) {
            int cb = (ks*64 + lg*16) ^ swz;
            bf16x8 af[4], bfv[4];
#pragma unroll
            for (int m = 0; m < 4; ++m) {
                af[m]  = *(const bf16x8*)(lA + (wr*64 + m*16 + lr)*128 + cb);
                bfv[m] = *(const bf16x8*)(lB + (wc*64 + m*16 + lr)*128 + cb);
            }
#pragma unroll
            for (int m = 0; m < 4; ++m)
#pragma unroll
                for (int n = 0; n < 4; ++n)
                    acc[m][n] = MFMA16(af[m], bfv[n], acc[m][n]);
        }
    }

    int rbase = row0 + wr*64 + lg*4;
    int cbase = col0 + wc*64 + lr;
#pragma unroll
    for (int n = 0; n < 4; ++n) {
        int col = cbase + n*16;
        float bv = bias[col];
#pragma unroll
        for (int m = 0; m < 4; ++m) {
            int rr = rbase + m*16;
#pragma unroll
            for (int j = 0; j < 4; ++j) {
                float val = acc[m][n][j] + bv;
                int r = rr + j;
                if constexpr (EPI == 0) {
                    int b = r >> 10, nn = r & 1023;
                    int which = col / CD;
                    int c2 = col - which * CD;
                    int head = c2 >> 6, d = c2 & 63;
                    __bf16* dst = (which == 0) ? qb : (which == 1 ? kb : vb);
                    dst[(((size_t)b*NHD + head)*SEQ + nn)*HDD + d] = (__bf16)val;
                } else if constexpr (EPI == 1) {
                    outf[(size_t)r*N + col] = res[(size_t)r*N + col] + val;
                } else {
                    float gl = 0.5f * val * (1.0f + erff(val * 0.70710678f));
                    outb[(size_t)r*N + col] = (__bf16)gl;
                }
            }
        }
    }
}

// ---------------- flash attention: q,k [bh][1024][64], vT [bh][64][1024] ------
__global__ __launch_bounds__(256)
void attn_kernel(const __bf16* __restrict__ q, const __bf16* __restrict__ k,
                 const __bf16* __restrict__ vT, __bf16* __restrict__ o)
{
    __shared__ alignas(16) __bf16 kls[64*64];
    __shared__ alignas(16) __bf16 vls[64*64];
    __shared__ alignas(16) __bf16 pls[4][16*72];

    int bid = blockIdx.x;
    int bh = bid >> 4;
    int qt = bid & 15;
    int b = bh / NHD, hh = bh - b*NHD;
    int tid = threadIdx.x, lane = tid & 63, w = tid >> 6;
    int lr = lane & 15, lg = lane >> 4;
    int swz = (lr & 7) << 4;

    int qrow = qt*64 + w*16 + lr;
    const __bf16* qp = q + (((size_t)bh << 10) + qrow)*HDD + lg*8;
    bf16x8 qf0 = *(const bf16x8*)qp;
    bf16x8 qf1 = *(const bf16x8*)(qp + 32);

    const __bf16* kb_ = k  + ((size_t)bh << 10)*HDD;
    const __bf16* vb_ = vT + ((size_t)bh << 6)*SEQ;

    float mst[4] = {-1e30f,-1e30f,-1e30f,-1e30f};
    float lst[4] = {0.f,0.f,0.f,0.f};
    f32x4 oacc[4] = {};

    char* kc = (char*)kls;
    char* vc = (char*)vls;

    for (int kv = 0; kv < SEQ; kv += 64) {
        __syncthreads();
#pragma unroll
        for (int i = 0; i < 2; ++i) {
            int s = ((w*2 + i) << 10) + lane*16;
            int r = s >> 7;
            int ch = ((s >> 4) & 7) ^ (r & 7);
            gload16(kb_ + (size_t)(kv + r)*HDD + ch*8, kc + ((w*2 + i) << 10));
            gload16(vb_ + (size_t)r*SEQ + kv + ch*8,   vc + ((w*2 + i) << 10));
        }
        __syncthreads();

        f32x4 sf[4] = {};
#pragma unroll
        for (int nf = 0; nf < 4; ++nf) {
            int rowK = nf*16 + lr;
            bf16x8 k0 = *(const bf16x8*)(kc + rowK*128 + ((lg*16) ^ swz));
            bf16x8 k1 = *(const bf16x8*)(kc + rowK*128 + ((64 + lg*16) ^ swz));
            sf[nf] = MFMA16(qf0, k0, sf[nf]);
            sf[nf] = MFMA16(qf1, k1, sf[nf]);
        }

        float sv[4][4];
#pragma unroll
        for (int nf = 0; nf < 4; ++nf)
#pragma unroll
            for (int j = 0; j < 4; ++j) sv[nf][j] = sf[nf][j] * 0.125f;

        float pm[4];
#pragma unroll
        for (int j = 0; j < 4; ++j)
            pm[j] = fmaxf(fmaxf(sv[0][j], sv[1][j]), fmaxf(sv[2][j], sv[3][j]));
#pragma unroll
        for (int j = 0; j < 4; ++j) {
#pragma unroll
            for (int off = 1; off < 16; off <<= 1)
                pm[j] = fmaxf(pm[j], __shfl_xor(pm[j], off));
        }
        float al[4];
#pragma unroll
        for (int j = 0; j < 4; ++j) {
            float mn = fmaxf(mst[j], pm[j]);
            al[j] = __expf(mst[j] - mn);
            mst[j] = mn;
        }
        float rs[4] = {0.f,0.f,0.f,0.f};
#pragma unroll
        for (int nf = 0; nf < 4; ++nf)
#pragma unroll
            for (int j = 0; j < 4; ++j) {
                float p = __expf(sv[nf][j] - mst[j]);
                sv[nf][j] = p;
                rs[j] += p;
            }
#pragma unroll
        for (int j = 0; j < 4; ++j) {
#pragma unroll
            for (int off = 1; off < 16; off <<= 1)
                rs[j] += __shfl_xor(rs[j], off);
            lst[j] = lst[j]*al[j] + rs[j];
        }
#pragma unroll
        for (int f = 0; f < 4; ++f)
#pragma unroll
            for (int j = 0; j < 4; ++j) oacc[f][j] *= al[j];

        __bf16* pw = pls[w];
#pragma unroll
        for (int nf = 0; nf < 4; ++nf)
#pragma unroll
            for (int j = 0; j < 4; ++j)
                pw[(lg*4 + j)*72 + nf*16 + lr] = (__bf16)sv[nf][j];
        asm volatile("s_waitcnt lgkmcnt(0)" ::: "memory");

#pragma unroll
        for (int ks = 0; ks < 2; ++ks) {
            bf16x8 pf = *(const bf16x8*)(pls[w] + lr*72 + ks*32 + lg*8);
#pragma unroll
            for (int f = 0; f < 4; ++f) {
                int rowV = f*16 + lr;
                bf16x8 vf = *(const bf16x8*)(vc + rowV*128 + ((ks*64 + lg*16) ^ swz));
                oacc[f] = MFMA16(pf, vf, oacc[f]);
            }
        }
    }

#pragma unroll
    for (int j = 0; j < 4; ++j) {
        float inv = 1.0f / lst[j];
        int row = qt*64 + w*16 + lg*4 + j;
#pragma unroll
        for (int f = 0; f < 4; ++f)
            o[(((size_t)b << 10) + row)*CD + hh*64 + f*16 + lr] = (__bf16)(oacc[f][j] * inv);
    }
}

// ------------------------------- launch ---------------------------------------
extern "C" void kernel_launch(void* const* d_in, const int* in_sizes, int n_in,
                              void* d_out, int out_size, void* d_ws, size_t ws_size,
                              hipStream_t stream)
{
    const float* x     = (const float*)d_in[0];
    const float* ln1g  = (const float*)d_in[1];
    const float* ln1b  = (const float*)d_in[2];
    const float* qkvw  = (const float*)d_in[3];
    const float* qkvb  = (const float*)d_in[4];
    const float* projw = (const float*)d_in[5];
    const float* projb = (const float*)d_in[6];
    const float* ln2g  = (const float*)d_in[7];
    const float* ln2b  = (const float*)d_in[8];
    const float* fc1w  = (const float*)d_in[9];
    const float* fc1b  = (const float*)d_in[10];
    const float* fc2w  = (const float*)d_in[11];
    const float* fc2b  = (const float*)d_in[12];
    float* out = (float*)d_out;

    char* p = (char*)d_ws;
    auto alloc = [&](size_t bytes) { char* r = p; p += (bytes + 255) & ~(size_t)255; return r; };
    __bf16* wqkvT  = (__bf16*)alloc((size_t)3*CD*CD*2);      // [2304][768]
    __bf16* wprojT = (__bf16*)alloc((size_t)CD*CD*2);        // [768][768]
    __bf16* wfc1T  = (__bf16*)alloc((size_t)HID*CD*2);       // [3072][768]
    __bf16* wfc2T  = (__bf16*)alloc((size_t)CD*HID*2);       // [768][3072]
    __bf16* hbuf   = (__bf16*)alloc((size_t)MT*CD*2);        // LN out / attn out
    __bf16* qbuf   = (__bf16*)alloc((size_t)BB*NHD*SEQ*HDD*2);
    __bf16* kbuf   = (__bf16*)alloc((size_t)BB*NHD*SEQ*HDD*2);
    __bf16* vbuf   = (__bf16*)alloc((size_t)BB*NHD*SEQ*HDD*2);
    __bf16* vtbuf  = (__bf16*)alloc((size_t)BB*NHD*SEQ*HDD*2);
    __bf16* hhbuf  = qbuf;   // reuse q+k+v+vT region: 4*25165824 B == MT*3072*2 B

    transpose_w<<<(CD/32)*(3*CD/32), 256, 0, stream>>>(qkvw,  wqkvT, CD, 3*CD);
    transpose_w<<<(CD/32)*(CD/32),   256, 0, stream>>>(projw, wprojT, CD, CD);
    transpose_w<<<(CD/32)*(HID/32),  256, 0, stream>>>(fc1w,  wfc1T, CD, HID);
    transpose_w<<<(HID/32)*(CD/32),  256, 0, stream>>>(fc2w,  wfc2T, HID, CD);

    ln_kernel<<<MT/4, 256, 0, stream>>>(x, ln1g, ln1b, hbuf);

    gemm_bt<0><<<(MT/128)*(3*CD/128), 256, 0, stream>>>(
        hbuf, wqkvT, qkvb, nullptr, nullptr, nullptr, qbuf, kbuf, vbuf, MT, 3*CD, CD);

    transpose_v<<<BB*NHD*64, 256, 0, stream>>>(vbuf, vtbuf);

    attn_kernel<<<BB*NHD*(SEQ/64), 256, 0, stream>>>(qbuf, kbuf, vtbuf, hbuf);

    gemm_bt<1><<<(MT/128)*(CD/128), 256, 0, stream>>>(
        hbuf, wprojT, projb, x, out, nullptr, nullptr, nullptr, nullptr, MT, CD, CD);

    ln_kernel<<<MT/4, 256, 0, stream>>>(out, ln2g, ln2b, hbuf);

    gemm_bt<2><<<(MT/128)*(HID/128), 256, 0, stream>>>(
        hbuf, wfc1T, fc1b, nullptr, nullptr, hhbuf, nullptr, nullptr, nullptr, MT, HID, CD);

    gemm_bt<1><<<(MT/128)*(CD/128), 256, 0, stream>>>(
        hhbuf, wfc2T, fc2b, out, out, nullptr, nullptr, nullptr, nullptr, MT, CD, HID);
}